// Round 1
// baseline (206.839 us; speedup 1.0000x reference)
//
#include <hip/hip_runtime.h>

#define DIM 128

// 32 lanes cooperatively score one edge: each lane loads a float4 (16B) of
// the 512B src row and dst row -> fully coalesced row reads. rel[r] row is
// held in registers (one float4 per lane), grid.y selects the relation.
__global__ __launch_bounds__(256) void distmult_kernel(
    const float* __restrict__ x,      // [N_NODES, DIM]
    const float* __restrict__ rel,    // [N_REL, DIM]
    const int* __restrict__ src,      // [N_REL, N_EDGES]
    const int* __restrict__ dst,      // [N_REL, N_EDGES]
    float* __restrict__ out,          // [N_REL, N_EDGES]
    int n_edges)
{
    const int r    = blockIdx.y;
    const int lane = threadIdx.x & 31;
    const int gpb  = blockDim.x >> 5;              // 32-lane groups per block

    const float4 c = ((const float4*)(rel + (size_t)r * DIM))[lane];
    const int*  srcR = src + (size_t)r * n_edges;
    const int*  dstR = dst + (size_t)r * n_edges;
    float*      outR = out + (size_t)r * n_edges;

    int e0     = blockIdx.x * gpb + (threadIdx.x >> 5);
    int stride = gridDim.x * gpb;

    for (int e = e0; e < n_edges; e += stride) {
        int s = srcR[e];
        int d = dstR[e];
        float4 a = ((const float4*)(x + (size_t)s * DIM))[lane];
        float4 b = ((const float4*)(x + (size_t)d * DIM))[lane];
        float p = a.x * b.x * c.x
                + a.y * b.y * c.y
                + a.z * b.z * c.z
                + a.w * b.w * c.w;
        // reduce across the 32-lane group (masks 16..1 never cross the
        // 32-lane halves of the wave64)
        p += __shfl_xor(p, 16);
        p += __shfl_xor(p, 8);
        p += __shfl_xor(p, 4);
        p += __shfl_xor(p, 2);
        p += __shfl_xor(p, 1);
        if (lane == 0) outR[e] = p;
    }
}

extern "C" void kernel_launch(void* const* d_in, const int* in_sizes, int n_in,
                              void* d_out, int out_size, void* d_ws, size_t ws_size,
                              hipStream_t stream) {
    const float* x   = (const float*)d_in[0];
    const float* rel = (const float*)d_in[1];
    const int*   src = (const int*)d_in[2];
    const int*   dst = (const int*)d_in[3];
    float*       out = (float*)d_out;

    const int n_rel   = in_sizes[1] / DIM;          // 3
    const int n_edges = in_sizes[2] / n_rel;        // 500000

    dim3 grid(2048, n_rel);
    distmult_kernel<<<grid, 256, 0, stream>>>(x, rel, src, dst, out, n_edges);
}

// Round 2
// 111.058 us; speedup vs baseline: 1.8624x; 1.8624x over previous
//
#include <hip/hip_runtime.h>

#define DIM 128

// ---------- pass 1: fp32 -> bf16 (RNE) conversion of the node table ----------
__device__ __forceinline__ unsigned bf16_rne(float f) {
    unsigned u = __float_as_uint(f);
    return (u + 0x7fffu + ((u >> 16) & 1u)) >> 16;
}

__global__ __launch_bounds__(256) void cvt_kernel(const float4* __restrict__ x,
                                                  uint2* __restrict__ y, int n4) {
    int i      = blockIdx.x * blockDim.x + threadIdx.x;
    int stride = gridDim.x * blockDim.x;
    for (; i < n4; i += stride) {
        float4 v = x[i];
        uint2 o;
        o.x = bf16_rne(v.x) | (bf16_rne(v.y) << 16);
        o.y = bf16_rne(v.z) | (bf16_rne(v.w) << 16);
        y[i] = o;
    }
}

// ---------- pass 2: gather bf16 rows, fp32 accumulate ----------
// 16 lanes per edge: each lane loads 16 B (8 bf16) of the 256 B src/dst rows.
// 4 edges per wave64 -> 8 dwordx4 gathers in flight per wave.
__device__ __forceinline__ float f_lo(unsigned u) { return __uint_as_float(u << 16); }
__device__ __forceinline__ float f_hi(unsigned u) { return __uint_as_float(u & 0xffff0000u); }

__global__ __launch_bounds__(256) void distmult_bf16_kernel(
    const unsigned short* __restrict__ xb,  // [N_NODES, DIM] bf16
    const float* __restrict__ rel,          // [N_REL, DIM] fp32
    const int* __restrict__ src,
    const int* __restrict__ dst,
    float* __restrict__ out,
    int n_edges)
{
    const int r    = blockIdx.y;
    const int lane = threadIdx.x & 15;
    const int gpb  = blockDim.x >> 4;   // 16-lane groups per block

    const float* relR = rel + (size_t)r * DIM + lane * 8;
    const float4 c0 = *(const float4*)(relR);
    const float4 c1 = *(const float4*)(relR + 4);

    const int* srcR = src + (size_t)r * n_edges;
    const int* dstR = dst + (size_t)r * n_edges;
    float*     outR = out + (size_t)r * n_edges;

    int e      = blockIdx.x * gpb + (threadIdx.x >> 4);
    int stride = gridDim.x * gpb;

    for (; e < n_edges; e += stride) {
        int s = srcR[e];
        int d = dstR[e];
        uint4 a = *(const uint4*)(xb + (size_t)s * DIM + lane * 8);
        uint4 b = *(const uint4*)(xb + (size_t)d * DIM + lane * 8);
        float p;
        p  = f_lo(a.x) * f_lo(b.x) * c0.x + f_hi(a.x) * f_hi(b.x) * c0.y;
        p += f_lo(a.y) * f_lo(b.y) * c0.z + f_hi(a.y) * f_hi(b.y) * c0.w;
        p += f_lo(a.z) * f_lo(b.z) * c1.x + f_hi(a.z) * f_hi(b.z) * c1.y;
        p += f_lo(a.w) * f_lo(b.w) * c1.z + f_hi(a.w) * f_hi(b.w) * c1.w;
        // reduce across the 16-lane group
        p += __shfl_xor(p, 8);
        p += __shfl_xor(p, 4);
        p += __shfl_xor(p, 2);
        p += __shfl_xor(p, 1);
        if (lane == 0) outR[e] = p;
    }
}

// ---------- fp32 fallback (round-1 kernel) if workspace too small ----------
__global__ __launch_bounds__(256) void distmult_f32_kernel(
    const float* __restrict__ x,
    const float* __restrict__ rel,
    const int* __restrict__ src,
    const int* __restrict__ dst,
    float* __restrict__ out,
    int n_edges)
{
    const int r    = blockIdx.y;
    const int lane = threadIdx.x & 31;
    const int gpb  = blockDim.x >> 5;

    const float4 c = ((const float4*)(rel + (size_t)r * DIM))[lane];
    const int*  srcR = src + (size_t)r * n_edges;
    const int*  dstR = dst + (size_t)r * n_edges;
    float*      outR = out + (size_t)r * n_edges;

    int e      = blockIdx.x * gpb + (threadIdx.x >> 5);
    int stride = gridDim.x * gpb;

    for (; e < n_edges; e += stride) {
        int s = srcR[e];
        int d = dstR[e];
        float4 a = ((const float4*)(x + (size_t)s * DIM))[lane];
        float4 b = ((const float4*)(x + (size_t)d * DIM))[lane];
        float p = a.x * b.x * c.x + a.y * b.y * c.y
                + a.z * b.z * c.z + a.w * b.w * c.w;
        p += __shfl_xor(p, 16);
        p += __shfl_xor(p, 8);
        p += __shfl_xor(p, 4);
        p += __shfl_xor(p, 2);
        p += __shfl_xor(p, 1);
        if (lane == 0) outR[e] = p;
    }
}

extern "C" void kernel_launch(void* const* d_in, const int* in_sizes, int n_in,
                              void* d_out, int out_size, void* d_ws, size_t ws_size,
                              hipStream_t stream) {
    const float* x   = (const float*)d_in[0];
    const float* rel = (const float*)d_in[1];
    const int*   src = (const int*)d_in[2];
    const int*   dst = (const int*)d_in[3];
    float*       out = (float*)d_out;

    const int n_rel   = in_sizes[1] / DIM;     // 3
    const int n_edges = in_sizes[2] / n_rel;   // 500000

    const size_t need = (size_t)in_sizes[0] * sizeof(unsigned short);
    dim3 grid(2048, n_rel);

    if (ws_size >= need) {
        const int n4 = in_sizes[0] / 4;
        cvt_kernel<<<2048, 256, 0, stream>>>((const float4*)x, (uint2*)d_ws, n4);
        distmult_bf16_kernel<<<grid, 256, 0, stream>>>(
            (const unsigned short*)d_ws, rel, src, dst, out, n_edges);
    } else {
        distmult_f32_kernel<<<grid, 256, 0, stream>>>(x, rel, src, dst, out, n_edges);
    }
}

// Round 3
// 66.840 us; speedup vs baseline: 3.0945x; 1.6615x over previous
//
#include <hip/hip_runtime.h>

#define DIM 128

// ---------- pass 1: fp32 -> int8 per-row symmetric quantization ----------
// One 32-lane group per row: lane loads float4 (4 dims), shfl-max for row
// absmax, quantize RNE, pack 4 int8 -> 1 dword, lane 0 writes scale.
__global__ __launch_bounds__(256) void quant_kernel(
    const float* __restrict__ x,      // [rows, DIM]
    unsigned* __restrict__ qt,        // [rows, 32] dwords (int8 packed)
    float* __restrict__ scales,       // [rows]
    int rows)
{
    const int lane = threadIdx.x & 31;
    const int rpb  = blockDim.x >> 5;
    int row        = blockIdx.x * rpb + (threadIdx.x >> 5);
    const int strd = gridDim.x * rpb;

    for (; row < rows; row += strd) {
        float4 v = ((const float4*)(x + (size_t)row * DIM))[lane];
        float m = fmaxf(fmaxf(fabsf(v.x), fabsf(v.y)),
                        fmaxf(fabsf(v.z), fabsf(v.w)));
        m = fmaxf(m, __shfl_xor(m, 16));
        m = fmaxf(m, __shfl_xor(m, 8));
        m = fmaxf(m, __shfl_xor(m, 4));
        m = fmaxf(m, __shfl_xor(m, 2));
        m = fmaxf(m, __shfl_xor(m, 1));
        const float inv = (m > 0.f) ? 127.f / m : 0.f;
        const float sc  = (m > 0.f) ? m / 127.f : 0.f;
        int q0 = (int)rintf(v.x * inv);
        int q1 = (int)rintf(v.y * inv);
        int q2 = (int)rintf(v.z * inv);
        int q3 = (int)rintf(v.w * inv);
        unsigned pk = ((unsigned)q0 & 0xffu)
                    | (((unsigned)q1 & 0xffu) << 8)
                    | (((unsigned)q2 & 0xffu) << 16)
                    | (((unsigned)q3 & 0xffu) << 24);
        qt[(size_t)row * 32 + lane] = pk;
        if (lane == 0) scales[row] = sc;
    }
}

// ---------- pass 2: int8 gather, exact int product, fp32 accumulate ----------
// 8 lanes per edge: each lane loads one uint4 (16 int8 = 16 dims) of the
// 128 B src/dst rows -> 8 edges in flight per wave64.
__device__ __forceinline__ float dot4_i8(unsigned a, unsigned b, float4 c) {
    int a0 = (int)(a << 24) >> 24, b0 = (int)(b << 24) >> 24;
    int a1 = (int)(a << 16) >> 24, b1 = (int)(b << 16) >> 24;
    int a2 = (int)(a <<  8) >> 24, b2 = (int)(b <<  8) >> 24;
    int a3 = (int)a         >> 24, b3 = (int)b         >> 24;
    return (float)(a0 * b0) * c.x + (float)(a1 * b1) * c.y
         + (float)(a2 * b2) * c.z + (float)(a3 * b3) * c.w;
}

__global__ __launch_bounds__(256) void distmult_i8_kernel(
    const unsigned* __restrict__ qt,     // [rows, 32] dwords
    const float* __restrict__ scales,    // [rows]
    const float* __restrict__ rel,       // [N_REL, DIM] fp32
    const int* __restrict__ src,
    const int* __restrict__ dst,
    float* __restrict__ out,
    int n_edges)
{
    const int r    = blockIdx.y;
    const int lane = threadIdx.x & 7;
    const int gpb  = blockDim.x >> 3;       // 8-lane groups per block

    const float* cR = rel + (size_t)r * DIM + lane * 16;
    const float4 c0 = ((const float4*)cR)[0];
    const float4 c1 = ((const float4*)cR)[1];
    const float4 c2 = ((const float4*)cR)[2];
    const float4 c3 = ((const float4*)cR)[3];

    const int* srcR = src + (size_t)r * n_edges;
    const int* dstR = dst + (size_t)r * n_edges;
    float*     outR = out + (size_t)r * n_edges;

    int e      = blockIdx.x * gpb + (threadIdx.x >> 3);
    int stride = gridDim.x * gpb;

    for (; e < n_edges; e += stride) {
        int s = __builtin_nontemporal_load(srcR + e);
        int d = __builtin_nontemporal_load(dstR + e);
        uint4 a = *(const uint4*)(qt + (size_t)s * 32 + lane * 4);
        uint4 b = *(const uint4*)(qt + (size_t)d * 32 + lane * 4);
        float p = dot4_i8(a.x, b.x, c0) + dot4_i8(a.y, b.y, c1)
                + dot4_i8(a.z, b.z, c2) + dot4_i8(a.w, b.w, c3);
        p += __shfl_xor(p, 4);
        p += __shfl_xor(p, 2);
        p += __shfl_xor(p, 1);
        if (lane == 0) {
            float v = p * scales[s] * scales[d];
            __builtin_nontemporal_store(v, outR + e);
        }
    }
}

// ---------- fp32 fallback if workspace too small ----------
__global__ __launch_bounds__(256) void distmult_f32_kernel(
    const float* __restrict__ x,
    const float* __restrict__ rel,
    const int* __restrict__ src,
    const int* __restrict__ dst,
    float* __restrict__ out,
    int n_edges)
{
    const int r    = blockIdx.y;
    const int lane = threadIdx.x & 31;
    const int gpb  = blockDim.x >> 5;

    const float4 c = ((const float4*)(rel + (size_t)r * DIM))[lane];
    const int*  srcR = src + (size_t)r * n_edges;
    const int*  dstR = dst + (size_t)r * n_edges;
    float*      outR = out + (size_t)r * n_edges;

    int e      = blockIdx.x * gpb + (threadIdx.x >> 5);
    int stride = gridDim.x * gpb;

    for (; e < n_edges; e += stride) {
        int s = srcR[e];
        int d = dstR[e];
        float4 a = ((const float4*)(x + (size_t)s * DIM))[lane];
        float4 b = ((const float4*)(x + (size_t)d * DIM))[lane];
        float p = a.x * b.x * c.x + a.y * b.y * c.y
                + a.z * b.z * c.z + a.w * b.w * c.w;
        p += __shfl_xor(p, 16);
        p += __shfl_xor(p, 8);
        p += __shfl_xor(p, 4);
        p += __shfl_xor(p, 2);
        p += __shfl_xor(p, 1);
        if (lane == 0) outR[e] = p;
    }
}

extern "C" void kernel_launch(void* const* d_in, const int* in_sizes, int n_in,
                              void* d_out, int out_size, void* d_ws, size_t ws_size,
                              hipStream_t stream) {
    const float* x   = (const float*)d_in[0];
    const float* rel = (const float*)d_in[1];
    const int*   src = (const int*)d_in[2];
    const int*   dst = (const int*)d_in[3];
    float*       out = (float*)d_out;

    const int n_rel   = in_sizes[1] / DIM;     // 3
    const int n_edges = in_sizes[2] / n_rel;   // 500000
    const int rows    = in_sizes[0] / DIM;     // 100000

    const size_t qt_bytes = (size_t)rows * DIM;            // int8 table
    const size_t sc_bytes = (size_t)rows * sizeof(float);
    dim3 grid(2048, n_rel);

    if (ws_size >= qt_bytes + sc_bytes) {
        unsigned* qt     = (unsigned*)d_ws;
        float*    scales = (float*)((char*)d_ws + qt_bytes);
        quant_kernel<<<2048, 256, 0, stream>>>(x, qt, scales, rows);
        distmult_i8_kernel<<<grid, 256, 0, stream>>>(
            qt, scales, rel, src, dst, out, n_edges);
    } else {
        distmult_f32_kernel<<<grid, 256, 0, stream>>>(x, rel, src, dst, out, n_edges);
    }
}